// Round 3
// baseline (130.382 us; speedup 1.0000x reference)
//
#include <hip/hip_runtime.h>
#include <hip/hip_bf16.h>
#include <math.h>

#define NN 100000
#define FF 256
#define EE 128
#define BB_ 10000
#define DD 32

typedef __attribute__((ext_vector_type(8))) short short8;
typedef __attribute__((ext_vector_type(4))) float f32x4;

__device__ __forceinline__ short f2bf(float f) {
  __hip_bfloat16 h = __float2bfloat16(f);   // HW RNE cvt
  union { __hip_bfloat16 h; short s; } u; u.h = h;
  return u.s;
}
__device__ __forceinline__ float bf2f(short s) {
  union { unsigned u; float f; } v;
  v.u = ((unsigned)(unsigned short)s) << 16;
  return v.f;
}

// ---- prep: We=W*z and bf16 [N][K] transposes of all weights ----
__global__ __launch_bounds__(256) void k_prep(
    const float* __restrict__ W, const float* __restrict__ qz,
    const float* __restrict__ a1w, const float* __restrict__ a2w,
    short* __restrict__ WeT, short* __restrict__ a1wTn,
    short* __restrict__ a1wTc, short* __restrict__ w2T) {
  int i = blockIdx.x * 256 + threadIdx.x;
  if (i < 32768) {                       // WeT[e][f] = W[f][e]*z(f)
    int e = i >> 8, f = i & 255;
    float g = qz[f];
    float s = 1.0f / (1.0f + expf(-g));
    float z = fminf(fmaxf(s * 1.2f - 0.1f, 0.0f), 1.0f);
    WeT[e * 256 + f] = f2bf(W[f * 128 + e] * z);
  } else if (i < 49152) {                // a1wTn[n][k] = a1w[k][n]
    int t = i - 32768; int n = t >> 7, k = t & 127;
    a1wTn[n * 128 + k] = f2bf(a1w[k * 128 + n]);
  } else if (i < 65536) {                // a1wTc[n][k] = a1w[128+k][n]
    int t = i - 49152; int n = t >> 7, k = t & 127;
    a1wTc[n * 128 + k] = f2bf(a1w[(128 + k) * 128 + n]);
  } else if (i < 81920) {                // w2T[n][k] = a2w[k][n]
    int t = i - 65536; int n = t >> 7, k = t & 127;
    w2T[n * 128 + k] = f2bf(a2w[k * 128 + n]);
  }
}

// ---- MFMA GEMM: C[M][128] = A(rows via idx)[M][K] @ BT[128][K]^T + bias ----
template <int K, bool AF32, bool OUTBF16>
__global__ __launch_bounds__(256) void k_mm(
    const void* __restrict__ Ap, const short* __restrict__ BT,
    const float* __restrict__ bias, const int* __restrict__ idx,
    void* __restrict__ Cp, int M) {
  __shared__ short As[128 * 64];
  __shared__ short Bs[128 * 64];
  const int tid = threadIdx.x;
  const int mb = blockIdx.x * 128;
  const int wave = tid >> 6, lane = tid & 63;
  const int wr = wave >> 1, wc = wave & 1;
  const int l15 = lane & 15, lg = lane >> 4;

  size_t abase[4];
#pragma unroll
  for (int s = 0; s < 4; ++s) {
    int row = (tid + s * 256) >> 3;
    int grow = mb + row;
    int gr = 0;
    if (grow < M) gr = idx ? idx[grow] : grow;
    abase[s] = (size_t)gr * K;
  }

  f32x4 acc[4][4];
#pragma unroll
  for (int i = 0; i < 4; ++i)
#pragma unroll
    for (int j = 0; j < 4; ++j) acc[i][j] = (f32x4){0.f, 0.f, 0.f, 0.f};

  for (int k0 = 0; k0 < K; k0 += 64) {
#pragma unroll
    for (int s = 0; s < 4; ++s) {
      int q = tid + s * 256;
      int row = q >> 3, c = q & 7;
      short8 av;
      if (AF32) {
        const float* ap = (const float*)Ap + abase[s] + k0 + c * 8;
        float4 f0 = *(const float4*)ap;
        float4 f1 = *(const float4*)(ap + 4);
        av[0] = f2bf(f0.x); av[1] = f2bf(f0.y);
        av[2] = f2bf(f0.z); av[3] = f2bf(f0.w);
        av[4] = f2bf(f1.x); av[5] = f2bf(f1.y);
        av[6] = f2bf(f1.z); av[7] = f2bf(f1.w);
      } else {
        av = *(const short8*)((const short*)Ap + abase[s] + k0 + c * 8);
      }
      *(short8*)(As + row * 64 + 8 * (c ^ (row & 7))) = av;
      short8 bv = *(const short8*)(BT + (size_t)row * K + k0 + c * 8);
      *(short8*)(Bs + row * 64 + 8 * (c ^ (row & 7))) = bv;
    }
    __syncthreads();
#pragma unroll
    for (int ks = 0; ks < 2; ++ks) {
      int c = ks * 4 + lg;
      short8 af[4], bfv[4];
#pragma unroll
      for (int i = 0; i < 4; ++i) {
        int r = wr * 64 + i * 16 + l15;
        af[i] = *(short8*)(As + r * 64 + 8 * (c ^ (r & 7)));
        int n = wc * 64 + i * 16 + l15;
        bfv[i] = *(short8*)(Bs + n * 64 + 8 * (c ^ (n & 7)));
      }
#pragma unroll
      for (int i = 0; i < 4; ++i)
#pragma unroll
        for (int j = 0; j < 4; ++j)
          acc[i][j] = __builtin_amdgcn_mfma_f32_16x16x32_bf16(
              af[i], bfv[j], acc[i][j], 0, 0, 0);
    }
    __syncthreads();
  }

  float bv4[4];
#pragma unroll
  for (int j = 0; j < 4; ++j) {
    int col = wc * 64 + j * 16 + l15;
    bv4[j] = bias ? bias[col] : 0.f;
  }
#pragma unroll
  for (int i = 0; i < 4; ++i) {
#pragma unroll
    for (int r = 0; r < 4; ++r) {
      int row = mb + wr * 64 + i * 16 + lg * 4 + r;
      if (row < M) {
#pragma unroll
        for (int j = 0; j < 4; ++j) {
          int col = wc * 64 + j * 16 + l15;
          float v = acc[i][j][r] + bv4[j];
          if (OUTBF16)
            ((short*)Cp)[(size_t)row * EE + col] = f2bf(v);
          else
            ((float*)Cp)[(size_t)row * EE + col] = v;
        }
      }
    }
  }
}

// ---- fused attention v3: one wave == one center, no barriers ----
__global__ __launch_bounds__(256) void k_attn3(
    const short* __restrict__ X, const short* __restrict__ Y,
    const float* __restrict__ P, const int* __restrict__ nodes,
    const int* __restrict__ nidx, const int* __restrict__ nmask,
    const short* __restrict__ w2T, const float* __restrict__ b2,
    const float* __restrict__ w3, const float* __restrict__ b3,
    float* __restrict__ out) {
  __shared__ int ni_s[4][32];
  __shared__ float sc_s[4][32];
  __shared__ float att_s[4][32];
  const int tid = threadIdx.x;
  const int wave = tid >> 6, lane = tid & 63;
  const int b = blockIdx.x * 4 + wave;      // this wave's center
  const int l15 = lane & 15, lg = lane >> 4;

  // stage this wave's neighbor ids (wave-local LDS; no barrier needed)
  if (lane < 32) ni_s[wave][lane] = nidx[b * DD + lane];

  const int nid0 = ni_s[wave][l15];         // row i=0: d = l15
  const int nid1 = ni_s[wave][16 + l15];    // row i=1: d = 16+l15
  const short* yr0 = Y + (size_t)nid0 * EE;
  const short* yr1 = Y + (size_t)nid1 * EE;
  const float* pr = P + (size_t)b * EE;

  f32x4 acc[2][8];
#pragma unroll
  for (int i = 0; i < 2; ++i)
#pragma unroll
    for (int j = 0; j < 8; ++j) acc[i][j] = (f32x4){0.f, 0.f, 0.f, 0.f};

#pragma unroll
  for (int ks = 0; ks < 4; ++ks) {
    const int k0 = ks * 32 + lg * 8;
    short8 y0 = *(const short8*)(yr0 + k0);
    short8 y1 = *(const short8*)(yr1 + k0);
    float4 pa = *(const float4*)(pr + k0);
    float4 pb = *(const float4*)(pr + k0 + 4);
    float pf[8] = {pa.x, pa.y, pa.z, pa.w, pb.x, pb.y, pb.z, pb.w};
    short8 a0, a1;
#pragma unroll
    for (int e = 0; e < 8; ++e) {
      a0[e] = f2bf(fmaxf(bf2f(y0[e]) + pf[e], 0.f));
      a1[e] = f2bf(fmaxf(bf2f(y1[e]) + pf[e], 0.f));
    }
    short8 bfv[8];
#pragma unroll
    for (int j = 0; j < 8; ++j)
      bfv[j] = *(const short8*)(w2T + (size_t)(j * 16 + l15) * EE + k0);
    __builtin_amdgcn_s_setprio(1);
#pragma unroll
    for (int j = 0; j < 8; ++j) {
      acc[0][j] = __builtin_amdgcn_mfma_f32_16x16x32_bf16(a0, bfv[j],
                                                          acc[0][j], 0, 0, 0);
      acc[1][j] = __builtin_amdgcn_mfma_f32_16x16x32_bf16(a1, bfv[j],
                                                          acc[1][j], 0, 0, 0);
    }
    __builtin_amdgcn_s_setprio(0);
  }

  // scores: s[row] = sum_col relu(h2[row][col]+b2[col]) * w3[col]
  float b2v[8], w3v[8];
#pragma unroll
  for (int j = 0; j < 8; ++j) {
    int col = j * 16 + l15;
    b2v[j] = b2[col];
    w3v[j] = w3[col];
  }
  float part[2][4];
#pragma unroll
  for (int i = 0; i < 2; ++i)
#pragma unroll
    for (int r = 0; r < 4; ++r) {
      float s = 0.f;
#pragma unroll
      for (int j = 0; j < 8; ++j)
        s += fmaxf(acc[i][j][r] + b2v[j], 0.f) * w3v[j];
      part[i][r] = s;
    }
#pragma unroll
  for (int off = 1; off <= 8; off <<= 1) {
#pragma unroll
    for (int i = 0; i < 2; ++i)
#pragma unroll
      for (int r = 0; r < 4; ++r) part[i][r] += __shfl_xor(part[i][r], off);
  }
  if (l15 == 0) {
#pragma unroll
    for (int i = 0; i < 2; ++i)
#pragma unroll
      for (int r = 0; r < 4; ++r)
        sc_s[wave][i * 16 + lg * 4 + r] = part[i][r];
  }

  // softmax over the 32 rows (rows duplicated in both 32-lane halves)
  const int row = lane & 31;
  const int m = nmask[(size_t)b * DD + row];
  float s = sc_s[wave][row] + b3[0];
  if (!m) s = -1e30f;
  float mx = s;
#pragma unroll
  for (int off = 1; off <= 16; off <<= 1) mx = fmaxf(mx, __shfl_xor(mx, off));
  float e = expf(s - mx);
  float sum = e;
#pragma unroll
  for (int off = 1; off <= 16; off <<= 1) sum += __shfl_xor(sum, off);
  if (lane < 32) att_s[wave][row] = e / sum;
  const bool has = (__ballot(m != 0) != 0ull);

  // agg: lane owns cols {2*lane, 2*lane+1}
  float a0 = 0.f, a1 = 0.f;
  if (has) {
#pragma unroll 4
    for (int d = 0; d < 32; ++d) {
      float a = att_s[wave][d];
      const short* xr = X + (size_t)ni_s[wave][d] * EE;
      unsigned xv = *(const unsigned*)(xr + 2 * lane);
      a0 += a * bf2f((short)(xv & 0xffffu));
      a1 += a * bf2f((short)(xv >> 16));
    }
  } else {
    const short* xr = X + (size_t)nodes[b] * EE;
    unsigned xv = *(const unsigned*)(xr + 2 * lane);
    a0 = bf2f((short)(xv & 0xffffu));
    a1 = bf2f((short)(xv >> 16));
  }
  *(float2*)(out + (size_t)b * EE + 2 * lane) = make_float2(a0, a1);
}

extern "C" void kernel_launch(void* const* d_in, const int* in_sizes, int n_in,
                              void* d_out, int out_size, void* d_ws,
                              size_t ws_size, hipStream_t stream) {
  const int* nodes = (const int*)d_in[0];
  const int* nidx = (const int*)d_in[1];
  const int* nmask = (const int*)d_in[2];
  const float* feature = (const float*)d_in[3];
  const float* W = (const float*)d_in[4];
  const float* bb = (const float*)d_in[5];
  const float* qz = (const float*)d_in[6];
  const float* a1w = (const float*)d_in[7];
  const float* a1b = (const float*)d_in[8];
  const float* a2w = (const float*)d_in[9];
  const float* a2b = (const float*)d_in[10];
  const float* a3w = (const float*)d_in[11];
  const float* a3b = (const float*)d_in[12];
  float* out = (float*)d_out;

  char* ws = (char*)d_ws;
  short* WeT   = (short*)(ws);                       // 64 KiB
  short* a1wTn = (short*)(ws + 65536);               // 32 KiB
  short* a1wTc = (short*)(ws + 98304);               // 32 KiB
  short* w2T   = (short*)(ws + 131072);              // 32 KiB
  short* Xb    = (short*)(ws + 163840);              // 25.6 MB bf16
  short* Yb    = (short*)(ws + 163840 + 25600000);   // 25.6 MB bf16
  float* Pv    = (float*)(ws + 163840 + 51200000);   // 5.12 MB fp32

  k_prep<<<320, 256, 0, stream>>>(W, qz, a1w, a2w, WeT, a1wTn, a1wTc, w2T);
  // X = feature @ We + b        [100000,256]x[256,128] -> bf16
  k_mm<256, true, true><<<(NN + 127) / 128, 256, 0, stream>>>(
      feature, WeT, bb, nullptr, Xb, NN);
  // Y = X @ att1_w[:128] + a1b  [100000,128]x[128,128] -> bf16
  k_mm<128, false, true><<<(NN + 127) / 128, 256, 0, stream>>>(
      Xb, a1wTn, a1b, nullptr, Yb, NN);
  // P = X[nodes] @ att1_w[128:] [10000,128]x[128,128] -> fp32
  k_mm<128, false, false><<<(BB_ + 127) / 128, 256, 0, stream>>>(
      Xb, a1wTc, nullptr, nodes, Pv, BB_);
  // fused attention + aggregation (1 wave per center)
  k_attn3<<<BB_ / 4, 256, 0, stream>>>(Xb, Yb, Pv, nodes, nidx, nmask, w2T,
                                       a2b, a3w, a3b, out);
}